// Round 3
// baseline (811.581 us; speedup 1.0000x reference)
//
#include <hip/hip_runtime.h>
#include <math.h>

typedef unsigned short ushort_t;
typedef __attribute__((ext_vector_type(8))) short short8;
typedef __attribute__((ext_vector_type(4))) float floatx4;
typedef __attribute__((ext_vector_type(8))) unsigned short ushortx8;

#define NROW 49408   // B*L = 256*193
#define MT   772     // NROW/64

__device__ __forceinline__ float b2f(ushort_t u){
  union { float f; unsigned int i; } v; v.i = ((unsigned int)u) << 16; return v.f;
}
__device__ __forceinline__ ushort_t f2b(float f){
  unsigned int i = __float_as_uint(f);
  unsigned int r = (i + 0x7FFFu + ((i >> 16) & 1u)) >> 16;
  return (ushort_t)r;
}

struct Args {
  const float *state,*C0,*C1,*C2,*C3,*C4,*C5;
  const float *Wq,*Wk,*Wv,*bq,*bk,*bv;
  const float *WCq,*WCk,*WCv,*bCq,*bCk,*bCv;
  const float *gQE,*beQE,*gKE,*beKE,*gVE,*beVE;
  const float *gQH,*beQH,*gKH,*beKH,*gVH,*beVH;
  const float *g1,*be1,*W1,*bl1,*W2,*bl2;
  float *qws,*kws,*vws;           // fp32 [B*H, 193, 32]
  ushort_t *attws,*z2ws;          // bf16 [NROW,64]
  ushort_t *weT,*whT,*w1T,*w2T;   // bf16 pre-transposed weights
  float *out;                     // fp32 [NROW,64]  <-- output IS float32
};

// ------------- weight convert+transpose: W[k][n] (f32) -> WT[n][k] (bf16) ---
__global__ __launch_bounds__(256) void k_prep(Args A){
  int i = blockIdx.x*256 + threadIdx.x;
  int stride = gridDim.x*256;
  const float* We[3] = {A.Wq, A.Wk, A.Wv};
  const float* Wh[3] = {A.WCq, A.WCk, A.WCv};
  for (int p=i; p<192*64; p+=stride){ int n=p>>6, k=p&63; A.weT[p] = f2b(We[n>>6][k*64 + (n&63)]); }
  for (int p=i; p<192*1536; p+=stride){ int n=p/1536, k=p-n*1536; A.whT[p] = f2b(Wh[n>>6][k*64 + (n&63)]); }
  for (int p=i; p<256*64; p+=stride){ int n=p>>6, k=p&63; A.w1T[p] = f2b(A.W1[k*256 + n]); }   // w1T[256][64]
  for (int p=i; p<64*256; p+=stride){ int n=p>>8, k=p&255; A.w2T[p] = f2b(A.W2[k*64 + n]); }   // w2T[64][256]
}

// ------------- projections + LN-gate -> q/k/v ws (fp32, [B,H,L,32]) ---------
#define LDA 40   // padded lds stride (32+8 ushorts)
__global__ __launch_bounds__(256) void k_proj(Args A){
  const int mb = blockIdx.x;
  const int t  = threadIdx.x;
  const int w  = t >> 6;
  const int l  = t & 63;
  const int lr = l & 15;
  const int lq = l >> 4;

  __shared__ __align__(16) ushort_t ldsA[64*LDA];
  __shared__ __align__(16) ushort_t ldsBt[192*LDA];
  __shared__ float lnE[64][65];
  __shared__ float lnH[64][65];

  floatx4 accH[3][4];
  floatx4 accE[3][4];
  #pragma unroll
  for (int jj=0;jj<3;jj++)
    #pragma unroll
    for (int ra=0;ra<4;ra++){ accH[jj][ra] = floatx4{0.f,0.f,0.f,0.f}; accE[jj][ra] = floatx4{0.f,0.f,0.f,0.f}; }

  const int arow = t >> 2, aseg = t & 3;
  const float* Cs[6] = {A.C0,A.C1,A.C2,A.C3,A.C4,A.C5};

  // ---- H branch: Ccat @ WC  (K = 1536) ----
  for (int kc = 0; kc < 48; ++kc){
    const int k0 = kc*32;
    const float* __restrict__ src = Cs[k0 >> 8] + (size_t)(mb*64 + arow)*256 + (k0 & 255) + aseg*8;
    float4 f0 = *(const float4*)(src);
    float4 f1 = *(const float4*)(src + 4);
    ushortx8 u;
    u[0]=f2b(f0.x); u[1]=f2b(f0.y); u[2]=f2b(f0.z); u[3]=f2b(f0.w);
    u[4]=f2b(f1.x); u[5]=f2b(f1.y); u[6]=f2b(f1.z); u[7]=f2b(f1.w);
    *(ushortx8*)(ldsA + arow*LDA + aseg*8) = u;
    #pragma unroll
    for (int i3=0;i3<3;i3++){
      int n = i3*64 + (t>>2); int kk = (t&3)*8;
      *(ushortx8*)(ldsBt + n*LDA + kk) = *(const ushortx8*)(A.whT + (size_t)n*1536 + k0 + kk);
    }
    __syncthreads();
    short8 a[4], b[3];
    #pragma unroll
    for (int ra=0;ra<4;ra++) a[ra] = *(const short8*)(ldsA + (16*ra + lr)*LDA + lq*8);
    #pragma unroll
    for (int jj=0;jj<3;jj++) b[jj] = *(const short8*)(ldsBt + (48*w + 16*jj + lr)*LDA + lq*8);
    #pragma unroll
    for (int jj=0;jj<3;jj++)
      #pragma unroll
      for (int ra=0;ra<4;ra++)
        accH[jj][ra] = __builtin_amdgcn_mfma_f32_16x16x32_bf16(a[ra], b[jj], accH[jj][ra], 0,0,0);
    __syncthreads();
  }

  // ---- E branch: state @ W  (K = 64) ----
  for (int kc = 0; kc < 2; ++kc){
    const int k0 = kc*32;
    const float* __restrict__ src = A.state + (size_t)(mb*64 + arow)*64 + k0 + aseg*8;
    float4 f0 = *(const float4*)(src);
    float4 f1 = *(const float4*)(src + 4);
    ushortx8 u;
    u[0]=f2b(f0.x); u[1]=f2b(f0.y); u[2]=f2b(f0.z); u[3]=f2b(f0.w);
    u[4]=f2b(f1.x); u[5]=f2b(f1.y); u[6]=f2b(f1.z); u[7]=f2b(f1.w);
    *(ushortx8*)(ldsA + arow*LDA + aseg*8) = u;
    #pragma unroll
    for (int i3=0;i3<3;i3++){
      int n = i3*64 + (t>>2); int kk = (t&3)*8;
      *(ushortx8*)(ldsBt + n*LDA + kk) = *(const ushortx8*)(A.weT + (size_t)n*64 + k0 + kk);
    }
    __syncthreads();
    short8 a[4], b[3];
    #pragma unroll
    for (int ra=0;ra<4;ra++) a[ra] = *(const short8*)(ldsA + (16*ra + lr)*LDA + lq*8);
    #pragma unroll
    for (int jj=0;jj<3;jj++) b[jj] = *(const short8*)(ldsBt + (48*w + 16*jj + lr)*LDA + lq*8);
    #pragma unroll
    for (int jj=0;jj<3;jj++)
      #pragma unroll
      for (int ra=0;ra<4;ra++)
        accE[jj][ra] = __builtin_amdgcn_mfma_f32_16x16x32_bf16(a[ra], b[jj], accE[jj][ra], 0,0,0);
    __syncthreads();
  }

  // ---- epilogue: per group g in {q,k,v}: bias, LN(E)*LN(H), store ----
  const float* bEs[3]  = {A.bq,  A.bk,  A.bv};
  const float* bHs[3]  = {A.bCq, A.bCk, A.bCv};
  const float* gEs[3]  = {A.gQE, A.gKE, A.gVE};
  const float* beEs[3] = {A.beQE,A.beKE,A.beVE};
  const float* gHs[3]  = {A.gQH, A.gKH, A.gVH};
  const float* beHs[3] = {A.beQH,A.beKH,A.beVH};
  float* outw[3] = {A.qws, A.kws, A.vws};

  for (int g=0; g<3; ++g){
    #pragma unroll
    for (int jj=0;jj<3;jj++){
      int jg = 3*w + jj;                    // global 16-col tile 0..11
      if ((jg >> 2) == g){
        int colL = (jg & 3)*16 + lr;        // col within group, 0..63
        float be_ = bEs[g][colL];
        float bh_ = bHs[g][colL];
        #pragma unroll
        for (int ra=0;ra<4;ra++)
          #pragma unroll
          for (int r=0;r<4;r++){
            int row = 16*ra + lq*4 + r;
            lnE[row][colL] = accE[jj][ra][r] + be_;
            lnH[row][colL] = accH[jj][ra][r] + bh_;
          }
      }
    }
    __syncthreads();
    {
      int r = t >> 2, q4 = t & 3;
      float sE=0.f, ssE=0.f, sH=0.f, ssH=0.f;
      #pragma unroll
      for (int c=0;c<16;c++){
        float e = lnE[r][q4*16+c]; sE += e; ssE += e*e;
        float h = lnH[r][q4*16+c]; sH += h; ssH += h*h;
      }
      sE  += __shfl_xor(sE,1);  sE  += __shfl_xor(sE,2);
      ssE += __shfl_xor(ssE,1); ssE += __shfl_xor(ssE,2);
      sH  += __shfl_xor(sH,1);  sH  += __shfl_xor(sH,2);
      ssH += __shfl_xor(ssH,1); ssH += __shfl_xor(ssH,2);
      float mE = sE*(1.f/64.f), vE = fmaxf(ssE*(1.f/64.f) - mE*mE, 0.f);
      float mH = sH*(1.f/64.f), vH = fmaxf(ssH*(1.f/64.f) - mH*mH, 0.f);
      float rE = rsqrtf(vE + 1e-5f), rH = rsqrtf(vH + 1e-5f);
      int G  = mb*64 + r;
      int bb = G / 193, lp = G - bb*193;
      float* ow = outw[g];
      #pragma unroll
      for (int c=0;c<16;c++){
        int cc = q4*16 + c;
        float e = (lnE[r][cc]-mE)*rE*gEs[g][cc] + beEs[g][cc];
        float h = (lnH[r][cc]-mH)*rH*gHs[g][cc] + beHs[g][cc];
        int hd = cc >> 5, d = cc & 31;
        ow[((size_t)(bb*2+hd)*193 + lp)*32 + d] = e*h;
      }
    }
    __syncthreads();
  }
}

// ------------- attention: one block per (b,h), query-per-thread -------------
__global__ __launch_bounds__(256) void k_attn(Args A){
  const int b = blockIdx.x, h = blockIdx.y;
  const int t = threadIdx.x;
  const size_t base = ((size_t)(b*2+h))*193*32;
  const float* __restrict__ kws = A.kws;
  const float* __restrict__ vws = A.vws;

  const int qrow = (t < 193) ? t : 192;
  float qreg[32], acc[32];
  {
    const float* qp = A.qws + base + qrow*32;
    #pragma unroll
    for (int d=0; d<32; d++){ qreg[d] = qp[d]; acc[d] = 0.f; }
  }
  float m = -1e30f, lsum = 0.f;
  for (int j=0; j<193; ++j){
    const float* kr = kws + base + j*32;   // wave-uniform address
    const float* vr = vws + base + j*32;
    float s = 0.f;
    #pragma unroll
    for (int d=0; d<32; d++) s += qreg[d]*kr[d];
    s *= 0.17677669529663687f;             // 1/sqrt(32)
    float mn = fmaxf(m, s);
    float al = __expf(m - mn);
    float p  = __expf(s - mn);
    lsum = lsum*al + p;
    #pragma unroll
    for (int d=0; d<32; d++) acc[d] = acc[d]*al + p*vr[d];
    m = mn;
  }
  if (t < 193){
    float inv = 1.f/lsum;
    size_t G = (size_t)b*193 + t;
    #pragma unroll
    for (int d=0; d<32; d++) A.attws[G*64 + h*32 + d] = f2b(acc[d]*inv);
  }
}

// ------------- Z1 = state+attn ; Z2 = LN(Z1) -> z2ws (bf16) -----------------
__global__ __launch_bounds__(256) void k_ln1(Args A){
  const int t = threadIdx.x, w = t>>6, l = t&63;
  const int G = blockIdx.x*4 + w;          // grid NROW/4 covers all rows
  float z1 = A.state[(size_t)G*64 + l] + b2f(A.attws[(size_t)G*64 + l]);
  float s = z1, sq = z1*z1;
  #pragma unroll
  for (int off=32; off>=1; off>>=1){ s += __shfl_xor(s,off); sq += __shfl_xor(sq,off); }
  float mean = s*(1.f/64.f);
  float var  = fmaxf(sq*(1.f/64.f) - mean*mean, 0.f);
  float z2 = (z1-mean)*rsqrtf(var+1e-5f)*A.g1[l] + A.be1[l];
  A.z2ws[(size_t)G*64 + l] = f2b(z2);
}

// ------------- fused FFN: gelu(Z2@W1+b1)@W2 + b2 + state + attn -> out ------
#define LZ2 72    // z2 tile padded stride
#define LZ3 264   // z3 tile padded stride
__global__ __launch_bounds__(256) void k_ffn(Args A){
  const int mb = blockIdx.x, t = threadIdx.x, w = t>>6, l = t&63, lr = l&15, lq = l>>4;
  __shared__ __align__(16) ushort_t z2t[64*LZ2];
  __shared__ __align__(16) ushort_t z3t[64*LZ3];

  #pragma unroll
  for (int i=0;i<2;i++){
    int p = i*2048 + t*8; int row = p>>6, col = p&63;
    *(ushortx8*)(z2t + row*LZ2 + col) = *(const ushortx8*)(A.z2ws + (size_t)mb*4096 + p);
  }
  __syncthreads();

  // FFN1: 64x256, K=64. wave w covers cols 64w..64w+63 (4 16-col tiles)
  floatx4 acc[4][4];
  #pragma unroll
  for (int jj=0;jj<4;jj++)
    #pragma unroll
    for (int ra=0;ra<4;ra++) acc[jj][ra] = floatx4{0.f,0.f,0.f,0.f};
  #pragma unroll
  for (int kc=0;kc<2;kc++){
    short8 a[4], b[4];
    #pragma unroll
    for (int ra=0;ra<4;ra++) a[ra] = *(const short8*)(z2t + (16*ra+lr)*LZ2 + kc*32 + lq*8);
    #pragma unroll
    for (int jj=0;jj<4;jj++) b[jj] = *(const short8*)(A.w1T + (size_t)(64*w + 16*jj + lr)*64 + kc*32 + lq*8);
    #pragma unroll
    for (int jj=0;jj<4;jj++)
      #pragma unroll
      for (int ra=0;ra<4;ra++)
        acc[jj][ra] = __builtin_amdgcn_mfma_f32_16x16x32_bf16(a[ra], b[jj], acc[jj][ra], 0,0,0);
  }
  #pragma unroll
  for (int jj=0;jj<4;jj++){
    int col = 64*w + 16*jj + lr;
    float bb = A.bl1[col];
    #pragma unroll
    for (int ra=0;ra<4;ra++)
      #pragma unroll
      for (int r=0;r<4;r++){
        int row = 16*ra + lq*4 + r;
        float x = acc[jj][ra][r] + bb;
        float gl = 0.5f*x*(1.0f + erff(x*0.70710678118654752f));
        z3t[row*LZ3 + col] = f2b(gl);
      }
  }
  __syncthreads();

  // FFN2: 64x64, K=256. wave w covers cols 16w..16w+15
  floatx4 o[4];
  #pragma unroll
  for (int ra=0;ra<4;ra++) o[ra] = floatx4{0.f,0.f,0.f,0.f};
  #pragma unroll
  for (int kc=0;kc<8;kc++){
    short8 a[4];
    short8 b = *(const short8*)(A.w2T + (size_t)(16*w + lr)*256 + kc*32 + lq*8);
    #pragma unroll
    for (int ra=0;ra<4;ra++) a[ra] = *(const short8*)(z3t + (16*ra+lr)*LZ3 + kc*32 + lq*8);
    #pragma unroll
    for (int ra=0;ra<4;ra++)
      o[ra] = __builtin_amdgcn_mfma_f32_16x16x32_bf16(a[ra], b, o[ra], 0,0,0);
  }
  int col = 16*w + lr;
  float bb = A.bl2[col];
  #pragma unroll
  for (int ra=0;ra<4;ra++)
    #pragma unroll
    for (int r=0;r<4;r++){
      int row = 16*ra + lq*4 + r;
      size_t idx = (size_t)(mb*64+row)*64 + col;
      A.out[idx] = o[ra][r] + bb + A.state[idx] + b2f(A.attws[idx]);  // fp32 store
    }
}

extern "C" void kernel_launch(void* const* d_in, const int* in_sizes, int n_in,
                              void* d_out, int out_size, void* d_ws, size_t ws_size,
                              hipStream_t stream){
  (void)in_sizes; (void)n_in; (void)out_size; (void)ws_size;
  Args A;
  A.state = (const float*)d_in[0];
  A.C0=(const float*)d_in[1]; A.C1=(const float*)d_in[2]; A.C2=(const float*)d_in[3];
  A.C3=(const float*)d_in[4]; A.C4=(const float*)d_in[5]; A.C5=(const float*)d_in[6];
  A.Wq=(const float*)d_in[7];  A.Wk=(const float*)d_in[8];  A.Wv=(const float*)d_in[9];
  A.bq=(const float*)d_in[10]; A.bk=(const float*)d_in[11]; A.bv=(const float*)d_in[12];
  A.WCq=(const float*)d_in[13]; A.WCk=(const float*)d_in[14]; A.WCv=(const float*)d_in[15];
  A.bCq=(const float*)d_in[16]; A.bCk=(const float*)d_in[17]; A.bCv=(const float*)d_in[18];
  A.gQE=(const float*)d_in[19]; A.beQE=(const float*)d_in[20];
  A.gKE=(const float*)d_in[21]; A.beKE=(const float*)d_in[22];
  A.gVE=(const float*)d_in[23]; A.beVE=(const float*)d_in[24];
  A.gQH=(const float*)d_in[25]; A.beQH=(const float*)d_in[26];
  A.gKH=(const float*)d_in[27]; A.beKH=(const float*)d_in[28];
  A.gVH=(const float*)d_in[29]; A.beVH=(const float*)d_in[30];
  A.g1=(const float*)d_in[31]; A.be1=(const float*)d_in[32];
  A.W1=(const float*)d_in[33]; A.bl1=(const float*)d_in[34];
  A.W2=(const float*)d_in[35]; A.bl2=(const float*)d_in[36];

  // workspace layout (~51.3 MB)
  char* ws = (char*)d_ws;
  size_t off = 0;
  const size_t rowf = (size_t)NROW*64*sizeof(float);       // 12.65 MB
  const size_t rowh = (size_t)NROW*64*2;                   // 6.32 MB
  A.qws  = (float*)(ws+off); off += rowf;
  A.kws  = (float*)(ws+off); off += rowf;
  A.vws  = (float*)(ws+off); off += rowf;
  A.attws= (ushort_t*)(ws+off); off += rowh;
  A.z2ws = (ushort_t*)(ws+off); off += rowh;
  A.weT  = (ushort_t*)(ws+off); off += 192*64*2;
  A.whT  = (ushort_t*)(ws+off); off += (size_t)192*1536*2;
  A.w1T  = (ushort_t*)(ws+off); off += 256*64*2;
  A.w2T  = (ushort_t*)(ws+off); off += 64*256*2;
  A.out  = (float*)d_out;

  k_prep <<<dim3(64),     dim3(256), 0, stream>>>(A);
  k_proj <<<dim3(MT),     dim3(256), 0, stream>>>(A);
  k_attn <<<dim3(256,2),  dim3(256), 0, stream>>>(A);
  k_ln1  <<<dim3(NROW/4), dim3(256), 0, stream>>>(A);
  k_ffn  <<<dim3(MT),     dim3(256), 0, stream>>>(A);
}